// Round 4
// baseline (516.818 us; speedup 1.0000x reference)
//
#include <hip/hip_runtime.h>

#define LOG2E 1.44269504088896f

typedef _Float16 f16;
typedef _Float16 f16x8 __attribute__((ext_vector_type(8)));
typedef float f32x4 __attribute__((ext_vector_type(4)));

#define NP 3
#define NN 4096
#define FF 1024
#define HH 8
#define DD 8
#define HD 64

// workspace byte offsets
#define OFF_F1S   0            // f32 [3][8][4096]      (f1 * log2e)
#define OFF_F2S   393216       // f16 [3][8][4096]      (f2 * log2e)
#define OFF_F2MAX 589824       // f32 [24]              (max_m f2s)
#define OFF_FTST  590080       // f16 [3][64][4096]     (fts transposed: [p][hd][n])
#define OFF_MULTI 2162944      // f32 [4096][3][64]     (per-path embeddings)

// output float offsets
#define OUT_FINAL 65536        // 4096*16
#define OUT_ALPHA 327680       // 65536 + 4096*64

// ---------------------------------------------------------------------------
// Kernel A: fts[p][n][hd] = inputs[p] @ W[p] (fp32), then f1/f2 epilogue and
// transposed fp16 copy of fts. Retiled 64->32 rows per block (grid 384) so
// all 256 CUs are covered (old grid 192 left 64 CUs idle, 1 wave/SIMD on the
// rest). 2x4 per-thread tile keeps the inner loop VALU-bound.
// ---------------------------------------------------------------------------
__global__ __launch_bounds__(256) void kA(const float* __restrict__ inp,
                                          const float* __restrict__ W,
                                          const float* __restrict__ a1w,
                                          const float* __restrict__ a1b,
                                          const float* __restrict__ a2w,
                                          const float* __restrict__ a2b,
                                          char* __restrict__ ws) {
    __shared__ float At[32 * 36];     // [k][row] transposed A tile (pad 36)
    __shared__ float Bt[32 * 64];     // [k][hd]
    __shared__ float ftile[32 * 68];  // [row][hd]
    const int tid = threadIdx.x;
    const int p = blockIdx.y;
    const int n0 = blockIdx.x * 32;

    const int tr = tid >> 4, tc = tid & 15;
    const int r0 = tr * 2, c0 = tc * 4;       // 2 rows x 4 cols per thread
    const int sr = tid >> 3, sak = (tid & 7) * 4;  // A staging: row, k-quad
    const int bc = tid & 63, bkq = tid >> 6;  // B staging
    const int hB = bc >> 3, dB = bc & 7;

    float acc[2][4] = {};

    for (int kb = 0; kb < 32; ++kb) {
        // stage A tile (transposed into LDS): 8 lanes cover one row's 32 k
        const float* asrc = inp + ((size_t)p * NN + n0 + sr) * FF + kb * 32 + sak;
        float4 av = *(const float4*)asrc;
        At[(sak + 0) * 36 + sr] = av.x;
        At[(sak + 1) * 36 + sr] = av.y;
        At[(sak + 2) * 36 + sr] = av.z;
        At[(sak + 3) * 36 + sr] = av.w;
        // stage B tile: Bt[k][hd] = W[p][h][f][d]
        #pragma unroll
        for (int i = 0; i < 8; ++i) {
            int k = bkq * 8 + i;
            Bt[k * 64 + bc] = W[(((size_t)p * HH + hB) * FF + kb * 32 + k) * DD + dB];
        }
        __syncthreads();
        #pragma unroll
        for (int k = 0; k < 32; ++k) {
            float2 a2 = *(const float2*)&At[k * 36 + r0];
            float4 bv = *(const float4*)&Bt[k * 64 + c0];
            float bb4[4] = {bv.x, bv.y, bv.z, bv.w};
            #pragma unroll
            for (int j = 0; j < 4; ++j) {
                acc[0][j] += a2.x * bb4[j];
                acc[1][j] += a2.y * bb4[j];
            }
        }
        __syncthreads();
    }
    // write fts tile to LDS
    #pragma unroll
    for (int i = 0; i < 2; ++i) {
        float4 o;
        o.x = acc[i][0]; o.y = acc[i][1]; o.z = acc[i][2]; o.w = acc[i][3];
        *(float4*)&ftile[(r0 + i) * 68 + c0] = o;
    }
    __syncthreads();

    float* f1s = (float*)(ws + OFF_F1S);
    f16* f2s = (f16*)(ws + OFF_F2S);
    // f1/f2 epilogue: exactly 256 tasks (32 rows x 8 heads)
    {
        int row = tid >> 3, h = tid & 7;
        const float* fb = &ftile[row * 68 + h * 8];
        float s1 = a1b[p * HH + h], s2 = a2b[p * HH + h];
        #pragma unroll
        for (int d = 0; d < 8; ++d) {
            float v = fb[d];
            s1 += v * a1w[((size_t)p * HH + h) * DD + d];
            s2 += v * a2w[((size_t)p * HH + h) * DD + d];
        }
        f1s[((size_t)p * HH + h) * NN + n0 + row] = s1 * LOG2E;
        f2s[((size_t)p * HH + h) * NN + n0 + row] = (f16)(s2 * LOG2E);
    }
    // transposed fp16 fts: ftsT[p][hd][n] (64 hd x 4 row-groups of 8)
    {
        f16* ftsT = (f16*)(ws + OFF_FTST);
        int cc2 = tid >> 2, rq = (tid & 3) * 8;
        union { f16 h[8]; uint4 u; } pk;
        #pragma unroll
        for (int i = 0; i < 8; ++i) pk.h[i] = (f16)ftile[(rq + i) * 68 + cc2];
        *(uint4*)(ftsT + ((size_t)p * HD + cc2) * NN + n0 + rq) = pk.u;
    }
}

// ---------------------------------------------------------------------------
// Kernel A2: f2smax[p][h] = max_m f2s[p][h][m]  (for the softmax upper bound)
// ---------------------------------------------------------------------------
__global__ __launch_bounds__(64) void kA2(char* __restrict__ ws) {
    const f16* f2s = (const f16*)(ws + OFF_F2S);
    float* fmax = (float*)(ws + OFF_F2MAX);
    int b = blockIdx.x;
    int lane = threadIdx.x;
    float v = -1e30f;
    for (int m = lane; m < NN; m += 64) v = fmaxf(v, (float)f2s[(size_t)b * NN + m]);
    #pragma unroll
    for (int off = 32; off >= 1; off >>= 1) v = fmaxf(v, __shfl_xor(v, off, 64));
    if (lane == 0) fmax[b] = v;
}

// ---------------------------------------------------------------------------
// Kernel B: fused attention, T14 async-STAGE split. Staging loads for chunk
// ch+1 are issued into registers BEFORE computing chunk ch; after the
// post-compute barrier the registers are written to LDS (vmcnt long since
// satisfied) and loads for ch+2 are issued. Removes L2 load latency from the
// per-chunk critical path. Same 2 barriers per chunk.
// ---------------------------------------------------------------------------
__global__ __launch_bounds__(256) void kB(const float* __restrict__ bias,
                                          const float* __restrict__ h_bias,
                                          char* __restrict__ ws) {
    __shared__ __align__(16) char smem[42768];
    f16* ftsL = (f16*)smem;               // [65][264] f16, row 64 = ones
    float* f2L = (float*)(smem + 34320);  // [8][264] f32

    const int tid = threadIdx.x;
    const int lane = tid & 63, wv = tid >> 6;
    const int c = lane & 15, kg = lane >> 4;
    const int p = blockIdx.y;
    const int n0 = blockIdx.x * 16;
    const int n = n0 + c;

    const float* f1s = (const float*)(ws + OFF_F1S);
    const f16* f2s = (const f16*)(ws + OFF_F2S);
    const float* fmax = (const float*)(ws + OFF_F2MAX);
    const f16* ftsG = (const f16*)(ws + OFF_FTST);
    float* multi = (float*)(ws + OFF_MULTI);

    // Per-head constants with -ub folded in:
    //   max(x,0.01x)-ub = max(x-ub, 0.01x-ub), x = f1+f2 (log2e-scaled)
    float A1[8], B1[8];
    #pragma unroll
    for (int h = 0; h < 8; ++h) {
        float f1v = f1s[((size_t)p * 8 + h) * NN + n];
        float fm = fmax[p * 8 + h];
        float x = f1v + fm;
        float lr = fmaxf(x, 0.01f * x);
        float ub = lr + 8.0f * LOG2E;  // bias < 8 assumed (N(0,1), max~5.95)
        A1[h] = f1v - ub;
        B1[h] = fmaf(0.01f, f1v, -ub);
    }

    // ones row for the denominator column
    for (int i = tid; i < 264; i += 256) ftsL[64 * 264 + i] = (f16)1.0f;

    // staging indices: 8-lane group sg covers a contiguous 128B row segment
    const int sg = tid >> 3, se = tid & 7;        // group, element-in-group
    const int srow = sg & 7, sq = sg >> 3;        // base row, column quarter
    const int f2r = tid >> 5, f2c = (tid & 31) * 8;  // f2 staging

    const f16* ftsP = ftsG + (size_t)p * HD * NN;
    const f16* f2P = f2s + (size_t)p * 8 * NN;

    // per-h LDS row select for the MFMA B operand (row 64 = ones for c>=8)
    const int rowsel = (c < 8) ? c * 264 : 64 * 264;
    const int hstep = (c < 8) ? 8 * 264 : 0;

    const float* bb_base = bias + ((size_t)p * NN + n) * NN + wv * 64 + kg * 8;

    f32x4 acc[8] = {};

    // staging register state (statically indexed via full unroll)
    uint4 rf[8];
    uint4 rf2v;

    auto issue = [&](int ch) {
        const f16* gsrc = ftsP + ch * 256 + sq * 64 + se * 8;
        #pragma unroll
        for (int k = 0; k < 8; ++k)
            rf[k] = *(const uint4*)(gsrc + (size_t)(srow + k * 8) * NN);
        rf2v = *(const uint4*)(f2P + (size_t)f2r * NN + ch * 256 + f2c);
    };
    auto commit = [&]() {
        f16* ldst = ftsL + srow * 264 + sq * 64 + se * 8;
        #pragma unroll
        for (int k = 0; k < 8; ++k) *(uint4*)(ldst + k * 8 * 264) = rf[k];
        union { uint4 u; f16 h[8]; } t16;
        t16.u = rf2v;
        float4 lo, hi;
        lo.x = (float)t16.h[0]; lo.y = (float)t16.h[1];
        lo.z = (float)t16.h[2]; lo.w = (float)t16.h[3];
        hi.x = (float)t16.h[4]; hi.y = (float)t16.h[5];
        hi.z = (float)t16.h[6]; hi.w = (float)t16.h[7];
        *(float4*)(f2L + f2r * 264 + f2c) = lo;
        *(float4*)(f2L + f2r * 264 + f2c + 4) = hi;
    };

    // prologue: stage chunk 0, issue chunk 1, load bias chunk 0
    issue(0);
    commit();
    issue(1);
    float4 uA0 = *(const float4*)(bb_base);
    float4 uA1 = *(const float4*)(bb_base + 4);
    float4 uB0 = *(const float4*)(bb_base + 32);
    float4 uB1 = *(const float4*)(bb_base + 36);
    __syncthreads();

    #pragma unroll 1
    for (int ch = 0; ch < 16; ++ch) {
        // prefetch bias for next chunk (clamped; last iter re-reads, cached)
        const int chn = (ch + 1 < 16) ? ch + 1 : 15;
        const float* bpn = bb_base + chn * 256;
        float4 nA0 = *(const float4*)(bpn);
        float4 nA1 = *(const float4*)(bpn + 4);
        float4 nB0 = *(const float4*)(bpn + 32);
        float4 nB1 = *(const float4*)(bpn + 36);

        #pragma unroll
        for (int s = 0; s < 2; ++s) {
            const int mloc = wv * 64 + s * 32 + kg * 8;
            float4 bv0 = s ? uB0 : uA0;
            float4 bv1 = s ? uB1 : uA1;
            float bbl[8] = {bv0.x * LOG2E, bv0.y * LOG2E, bv0.z * LOG2E, bv0.w * LOG2E,
                            bv1.x * LOG2E, bv1.y * LOG2E, bv1.z * LOG2E, bv1.w * LOG2E};
            #pragma unroll
            for (int h = 0; h < 8; ++h) {
                const float* f2p = f2L + h * 264 + mloc;
                float4 f2a = *(const float4*)f2p;
                float4 f2b = *(const float4*)(f2p + 4);
                float f2arr[8] = {f2a.x, f2a.y, f2a.z, f2a.w, f2b.x, f2b.y, f2b.z, f2b.w};
                f16x8 bf = *(const f16x8*)(ftsL + rowsel + h * hstep + mloc);
                union { f16x8 v; f16 e[8]; } af;
                #pragma unroll
                for (int j = 0; j < 8; ++j) {
                    float t1 = f2arr[j] + A1[h];
                    float t2 = fmaf(0.01f, f2arr[j], B1[h]);
                    af.e[j] = (f16)__builtin_amdgcn_exp2f(fmaxf(t1, t2) + bbl[j]);
                }
                acc[h] = __builtin_amdgcn_mfma_f32_16x16x32_f16(af.v, bf, acc[h], 0, 0, 0);
            }
        }
        __syncthreads();   // all waves done reading LDS for chunk ch
        if (ch < 15) {
            commit();                      // write chunk ch+1 (regs ready)
            if (ch < 14) issue(ch + 2);    // in flight during next compute
            __syncthreads();               // chunk ch+1 visible
        }
        uA0 = nA0; uA1 = nA1; uB0 = nB0; uB1 = nB1;
    }

    // epilogue: cross-wave reduction of D-frags (+denominator col 8) via LDS
    float* red = (float*)smem;  // [4][8][16][9]
    #pragma unroll
    for (int h = 0; h < 8; ++h) {
        if (c <= 8) {
            #pragma unroll
            for (int r = 0; r < 4; ++r)
                red[((wv * 8 + h) * 16 + kg * 4 + r) * 9 + c] = acc[h][r];
        }
    }
    __syncthreads();
    #pragma unroll
    for (int rep = 0; rep < 4; ++rep) {
        int idx = tid + rep * 256;
        int R = idx >> 6, hd = idx & 63;
        int h = hd >> 3, d = hd & 7;
        float v = 0.f, l = 0.f;
        #pragma unroll
        for (int w = 0; w < 4; ++w) {
            v += red[((w * 8 + h) * 16 + R) * 9 + d];
            l += red[((w * 8 + h) * 16 + R) * 9 + 8];
        }
        float o = v / l + h_bias[(p * 8 + h) * 8 + d];
        o = o > 0.f ? o : (__builtin_amdgcn_exp2f(o * LOG2E) - 1.0f);  // elu
        multi[((size_t)(n0 + R) * NP + p) * HD + hd] = o;
    }
}

// ---------------------------------------------------------------------------
// Kernel C: semantic attention + classifier. 16 nodes per block.
// ---------------------------------------------------------------------------
__global__ __launch_bounds__(256) void kC(const float* __restrict__ Ws,
                                          const float* __restrict__ bsv,
                                          const float* __restrict__ uv,
                                          const float* __restrict__ Wc,
                                          const float* __restrict__ bcv,
                                          char* __restrict__ ws,
                                          float* __restrict__ out) {
    __shared__ float WsL[64 * 128];
    __shared__ float mult[16 * 3 * 64];
    __shared__ float WcL[64 * 16];
    __shared__ float uL[128], bsL[128], bcL[16];
    __shared__ float vred[16 * 3 * 16];
    __shared__ float alphaL[16 * 3];
    __shared__ float fin[16 * 64];
    const int tid = threadIdx.x;
    const int n0 = blockIdx.x * 16;
    const float* multi = (const float*)(ws + OFF_MULTI);

    for (int i = tid; i < 64 * 128; i += 256) WsL[i] = Ws[i];
    for (int i = tid; i < 3072; i += 256) mult[i] = multi[(size_t)n0 * 192 + i];
    for (int i = tid; i < 1024; i += 256) WcL[i] = Wc[i];
    if (tid < 128) { uL[tid] = uv[tid]; bsL[tid] = bsv[tid]; }
    if (tid < 16) bcL[tid] = bcv[tid];
    __syncthreads();

    const int nl = tid >> 4, j = tid & 15;
    for (int p = 0; p < 3; ++p) {
        float va[8] = {};
        for (int e = 0; e < 64; ++e) {
            float me = mult[(nl * 3 + p) * 64 + e];
            #pragma unroll
            for (int i = 0; i < 8; ++i) va[i] += me * WsL[e * 128 + j + 16 * i];
        }
        float part = 0.f;
        #pragma unroll
        for (int i = 0; i < 8; ++i) part += tanhf(va[i] + bsL[j + 16 * i]) * uL[j + 16 * i];
        vred[(nl * 3 + p) * 16 + j] = part;
    }
    __syncthreads();
    if (tid < 16) {
        float sc[3];
        for (int p = 0; p < 3; ++p) {
            float s = 0.f;
            for (int jj = 0; jj < 16; ++jj) s += vred[(tid * 3 + p) * 16 + jj];
            sc[p] = s;
        }
        float mx = fmaxf(sc[0], fmaxf(sc[1], sc[2]));
        float e0 = __builtin_amdgcn_exp2f((sc[0] - mx) * LOG2E);
        float e1 = __builtin_amdgcn_exp2f((sc[1] - mx) * LOG2E);
        float e2 = __builtin_amdgcn_exp2f((sc[2] - mx) * LOG2E);
        float inv = 1.f / (e0 + e1 + e2);
        float a0 = e0 * inv, a1 = e1 * inv, a2 = e2 * inv;
        alphaL[tid * 3 + 0] = a0; alphaL[tid * 3 + 1] = a1; alphaL[tid * 3 + 2] = a2;
        out[OUT_ALPHA + (size_t)(n0 + tid) * 3 + 0] = a0;
        out[OUT_ALPHA + (size_t)(n0 + tid) * 3 + 1] = a1;
        out[OUT_ALPHA + (size_t)(n0 + tid) * 3 + 2] = a2;
    }
    __syncthreads();
    for (int idx = tid; idx < 1024; idx += 256) {
        int nn2 = idx >> 6, e = idx & 63;
        float f = 0.f;
        for (int p = 0; p < 3; ++p) f += mult[(nn2 * 3 + p) * 64 + e] * alphaL[nn2 * 3 + p];
        fin[nn2 * 64 + e] = f;
        out[OUT_FINAL + (size_t)(n0 + nn2) * 64 + e] = f;
    }
    __syncthreads();
    {
        int nn2 = tid >> 4, cc2 = tid & 15;
        float lg = bcL[cc2];
        for (int e = 0; e < 64; ++e) lg += fin[nn2 * 64 + e] * WcL[e * 16 + cc2];
        out[(size_t)(n0 + nn2) * 16 + cc2] = lg;
    }
}

extern "C" void kernel_launch(void* const* d_in, const int* in_sizes, int n_in,
                              void* d_out, int out_size, void* d_ws, size_t ws_size,
                              hipStream_t stream) {
    (void)in_sizes; (void)n_in; (void)out_size; (void)ws_size;
    const float* inp = (const float*)d_in[0];
    const float* bias = (const float*)d_in[1];
    const float* W = (const float*)d_in[2];
    const float* a1w = (const float*)d_in[3];
    const float* a1b = (const float*)d_in[4];
    const float* a2w = (const float*)d_in[5];
    const float* a2b = (const float*)d_in[6];
    const float* hb = (const float*)d_in[7];
    const float* Wsv = (const float*)d_in[8];
    const float* bsv = (const float*)d_in[9];
    const float* uv = (const float*)d_in[10];
    const float* Wcv = (const float*)d_in[11];
    const float* bcv = (const float*)d_in[12];
    char* ws = (char*)d_ws;
    float* out = (float*)d_out;

    hipLaunchKernelGGL(kA, dim3(128, 3), dim3(256), 0, stream, inp, W, a1w, a1b, a2w, a2b, ws);
    hipLaunchKernelGGL(kA2, dim3(24), dim3(64), 0, stream, ws);
    hipLaunchKernelGGL(kB, dim3(256, 3), dim3(256), 0, stream, bias, hb, ws);
    hipLaunchKernelGGL(kC, dim3(256), dim3(256), 0, stream, Wsv, bsv, uv, Wcv, bcv, ws, out);
}

// Round 5
// 425.778 us; speedup vs baseline: 1.2138x; 1.2138x over previous
//
#include <hip/hip_runtime.h>

#define LOG2E 1.44269504088896f

typedef _Float16 f16;
typedef _Float16 f16x8 __attribute__((ext_vector_type(8)));
typedef float f32x4 __attribute__((ext_vector_type(4)));

#define NP 3
#define NN 4096
#define FF 1024
#define HH 8
#define DD 8
#define HD 64

// workspace byte offsets
#define OFF_F1S   0            // f32 [3][8][4096]      (f1 * log2e)
#define OFF_F2S   393216       // f16 [3][8][4096]      (f2 * log2e)
#define OFF_F2MAX 589824       // f32 [24]              (max_m f2s)
#define OFF_FTST  590080       // f16 [3][64][4096]     (fts transposed: [p][hd][n])
#define OFF_MULTI 2162944      // f32 [4096][3][64]     (per-path embeddings)

// output float offsets
#define OUT_FINAL 65536        // 4096*16
#define OUT_ALPHA 327680       // 65536 + 4096*64

// ---------------------------------------------------------------------------
// Kernel A: fts[p][n][hd] = inputs[p] @ W[p] (fp32), then f1/f2 epilogue and
// transposed fp16 copy of fts. 32 rows per block (grid 384) so all 256 CUs
// are covered. 2x4 per-thread tile keeps the inner loop VALU-bound.
// ---------------------------------------------------------------------------
__global__ __launch_bounds__(256) void kA(const float* __restrict__ inp,
                                          const float* __restrict__ W,
                                          const float* __restrict__ a1w,
                                          const float* __restrict__ a1b,
                                          const float* __restrict__ a2w,
                                          const float* __restrict__ a2b,
                                          char* __restrict__ ws) {
    __shared__ float At[32 * 36];     // [k][row] transposed A tile (pad 36)
    __shared__ float Bt[32 * 64];     // [k][hd]
    __shared__ float ftile[32 * 68];  // [row][hd]
    const int tid = threadIdx.x;
    const int p = blockIdx.y;
    const int n0 = blockIdx.x * 32;

    const int tr = tid >> 4, tc = tid & 15;
    const int r0 = tr * 2, c0 = tc * 4;       // 2 rows x 4 cols per thread
    const int sr = tid >> 3, sak = (tid & 7) * 4;  // A staging: row, k-quad
    const int bc = tid & 63, bkq = tid >> 6;  // B staging
    const int hB = bc >> 3, dB = bc & 7;

    float acc[2][4] = {};

    for (int kb = 0; kb < 32; ++kb) {
        // stage A tile (transposed into LDS): 8 lanes cover one row's 32 k
        const float* asrc = inp + ((size_t)p * NN + n0 + sr) * FF + kb * 32 + sak;
        float4 av = *(const float4*)asrc;
        At[(sak + 0) * 36 + sr] = av.x;
        At[(sak + 1) * 36 + sr] = av.y;
        At[(sak + 2) * 36 + sr] = av.z;
        At[(sak + 3) * 36 + sr] = av.w;
        // stage B tile: Bt[k][hd] = W[p][h][f][d]
        #pragma unroll
        for (int i = 0; i < 8; ++i) {
            int k = bkq * 8 + i;
            Bt[k * 64 + bc] = W[(((size_t)p * HH + hB) * FF + kb * 32 + k) * DD + dB];
        }
        __syncthreads();
        #pragma unroll
        for (int k = 0; k < 32; ++k) {
            float2 a2 = *(const float2*)&At[k * 36 + r0];
            float4 bv = *(const float4*)&Bt[k * 64 + c0];
            float bb4[4] = {bv.x, bv.y, bv.z, bv.w};
            #pragma unroll
            for (int j = 0; j < 4; ++j) {
                acc[0][j] += a2.x * bb4[j];
                acc[1][j] += a2.y * bb4[j];
            }
        }
        __syncthreads();
    }
    // write fts tile to LDS
    #pragma unroll
    for (int i = 0; i < 2; ++i) {
        float4 o;
        o.x = acc[i][0]; o.y = acc[i][1]; o.z = acc[i][2]; o.w = acc[i][3];
        *(float4*)&ftile[(r0 + i) * 68 + c0] = o;
    }
    __syncthreads();

    float* f1s = (float*)(ws + OFF_F1S);
    f16* f2s = (f16*)(ws + OFF_F2S);
    // f1/f2 epilogue: exactly 256 tasks (32 rows x 8 heads)
    {
        int row = tid >> 3, h = tid & 7;
        const float* fb = &ftile[row * 68 + h * 8];
        float s1 = a1b[p * HH + h], s2 = a2b[p * HH + h];
        #pragma unroll
        for (int d = 0; d < 8; ++d) {
            float v = fb[d];
            s1 += v * a1w[((size_t)p * HH + h) * DD + d];
            s2 += v * a2w[((size_t)p * HH + h) * DD + d];
        }
        f1s[((size_t)p * HH + h) * NN + n0 + row] = s1 * LOG2E;
        f2s[((size_t)p * HH + h) * NN + n0 + row] = (f16)(s2 * LOG2E);
    }
    // transposed fp16 fts: ftsT[p][hd][n] (64 hd x 4 row-groups of 8)
    {
        f16* ftsT = (f16*)(ws + OFF_FTST);
        int cc2 = tid >> 2, rq = (tid & 3) * 8;
        union { f16 h[8]; uint4 u; } pk;
        #pragma unroll
        for (int i = 0; i < 8; ++i) pk.h[i] = (f16)ftile[(rq + i) * 68 + cc2];
        *(uint4*)(ftsT + ((size_t)p * HD + cc2) * NN + n0 + rq) = pk.u;
    }
}

// ---------------------------------------------------------------------------
// Kernel A2: f2smax[p][h] = max_m f2s[p][h][m]  (for the softmax upper bound)
// ---------------------------------------------------------------------------
__global__ __launch_bounds__(64) void kA2(char* __restrict__ ws) {
    const f16* f2s = (const f16*)(ws + OFF_F2S);
    float* fmax = (float*)(ws + OFF_F2MAX);
    int b = blockIdx.x;
    int lane = threadIdx.x;
    float v = -1e30f;
    for (int m = lane; m < NN; m += 64) v = fmaxf(v, (float)f2s[(size_t)b * NN + m]);
    #pragma unroll
    for (int off = 32; off >= 1; off >>= 1) v = fmaxf(v, __shfl_xor(v, off, 64));
    if (lane == 0) fmax[b] = v;
}

// ---------------------------------------------------------------------------
// Kernel B: fused attention, T14 async-STAGE split, spill-proofed.
// Round-4 lesson: the rf[8] staging ARRAY (in lambdas, live across a barrier
// in a #pragma unroll 1 loop) was demoted to scratch -> 350 MB of HBM spill
// traffic. Fix: NAMED uint4 registers via macros (every access is a
// compile-time register name) + __launch_bounds__(256,3) (LDS already caps
// at 3 blocks/CU, so raising the VGPR cap to ~168 is free).
// ---------------------------------------------------------------------------
__global__ __launch_bounds__(256, 3) void kB(const float* __restrict__ bias,
                                             const float* __restrict__ h_bias,
                                             char* __restrict__ ws) {
    __shared__ __align__(16) char smem[42768];
    f16* ftsL = (f16*)smem;               // [65][264] f16, row 64 = ones
    float* f2L = (float*)(smem + 34320);  // [8][264] f32

    const int tid = threadIdx.x;
    const int lane = tid & 63, wv = tid >> 6;
    const int c = lane & 15, kg = lane >> 4;
    const int p = blockIdx.y;
    const int n0 = blockIdx.x * 16;
    const int n = n0 + c;

    const float* f1s = (const float*)(ws + OFF_F1S);
    const f16* f2s = (const f16*)(ws + OFF_F2S);
    const float* fmax = (const float*)(ws + OFF_F2MAX);
    const f16* ftsG = (const f16*)(ws + OFF_FTST);
    float* multi = (float*)(ws + OFF_MULTI);

    // Per-head constants with -ub folded in:
    //   max(x,0.01x)-ub = max(x-ub, 0.01x-ub), x = f1+f2 (log2e-scaled)
    float A1[8], B1[8];
    #pragma unroll
    for (int h = 0; h < 8; ++h) {
        float f1v = f1s[((size_t)p * 8 + h) * NN + n];
        float fm = fmax[p * 8 + h];
        float x = f1v + fm;
        float lr = fmaxf(x, 0.01f * x);
        float ub = lr + 8.0f * LOG2E;  // bias < 8 assumed (N(0,1), max~5.95)
        A1[h] = f1v - ub;
        B1[h] = fmaf(0.01f, f1v, -ub);
    }

    // ones row for the denominator column
    for (int i = tid; i < 264; i += 256) ftsL[64 * 264 + i] = (f16)1.0f;

    // staging indices: 8-lane group sg covers a contiguous 128B row segment
    const int sg = tid >> 3, se = tid & 7;        // group, element-in-group
    const int srow = sg & 7, sq = sg >> 3;        // base row, column quarter
    const int f2r = tid >> 5, f2c = (tid & 31) * 8;  // f2 staging

    const f16* ftsP = ftsG + (size_t)p * HD * NN + sq * 64 + se * 8;
    const f16* f2P = f2s + (size_t)p * 8 * NN + (size_t)f2r * NN + f2c;
    f16* ldst = ftsL + srow * 264 + sq * 64 + se * 8;

    // per-h LDS row select for the MFMA B operand (row 64 = ones for c>=8)
    const int rowsel = (c < 8) ? c * 264 : 64 * 264;
    const int hstep = (c < 8) ? 8 * 264 : 0;

    const float* bb_base = bias + ((size_t)p * NN + n) * NN + wv * 64 + kg * 8;

    f32x4 acc[8] = {};

    // T14 staging state: NAMED registers (never an indexed array)
    uint4 r0, r1, r2, r3, r4, r5, r6, r7, rv;

#define ISSUE(ch) do { \
        const f16* gs_ = ftsP + (ch) * 256; \
        r0 = *(const uint4*)(gs_ + (size_t)(srow +  0) * NN); \
        r1 = *(const uint4*)(gs_ + (size_t)(srow +  8) * NN); \
        r2 = *(const uint4*)(gs_ + (size_t)(srow + 16) * NN); \
        r3 = *(const uint4*)(gs_ + (size_t)(srow + 24) * NN); \
        r4 = *(const uint4*)(gs_ + (size_t)(srow + 32) * NN); \
        r5 = *(const uint4*)(gs_ + (size_t)(srow + 40) * NN); \
        r6 = *(const uint4*)(gs_ + (size_t)(srow + 48) * NN); \
        r7 = *(const uint4*)(gs_ + (size_t)(srow + 56) * NN); \
        rv = *(const uint4*)(f2P + (ch) * 256); \
    } while (0)

#define COMMIT() do { \
        *(uint4*)(ldst + 0 * 8 * 264) = r0; \
        *(uint4*)(ldst + 1 * 8 * 264) = r1; \
        *(uint4*)(ldst + 2 * 8 * 264) = r2; \
        *(uint4*)(ldst + 3 * 8 * 264) = r3; \
        *(uint4*)(ldst + 4 * 8 * 264) = r4; \
        *(uint4*)(ldst + 5 * 8 * 264) = r5; \
        *(uint4*)(ldst + 6 * 8 * 264) = r6; \
        *(uint4*)(ldst + 7 * 8 * 264) = r7; \
        union { uint4 u; f16 h[8]; } t16_; \
        t16_.u = rv; \
        float4 lo_, hi_; \
        lo_.x = (float)t16_.h[0]; lo_.y = (float)t16_.h[1]; \
        lo_.z = (float)t16_.h[2]; lo_.w = (float)t16_.h[3]; \
        hi_.x = (float)t16_.h[4]; hi_.y = (float)t16_.h[5]; \
        hi_.z = (float)t16_.h[6]; hi_.w = (float)t16_.h[7]; \
        *(float4*)(f2L + f2r * 264 + f2c) = lo_; \
        *(float4*)(f2L + f2r * 264 + f2c + 4) = hi_; \
    } while (0)

    // prologue: stage chunk 0, issue chunk 1, load bias chunk 0
    ISSUE(0);
    COMMIT();
    ISSUE(1);
    float4 uA0 = *(const float4*)(bb_base);
    float4 uA1 = *(const float4*)(bb_base + 4);
    float4 uB0 = *(const float4*)(bb_base + 32);
    float4 uB1 = *(const float4*)(bb_base + 36);
    __syncthreads();

    #pragma unroll 1
    for (int ch = 0; ch < 16; ++ch) {
        // prefetch bias for next chunk (clamped; last iter re-reads, cached)
        const int chn = (ch + 1 < 16) ? ch + 1 : 15;
        const float* bpn = bb_base + chn * 256;
        float4 nA0 = *(const float4*)(bpn);
        float4 nA1 = *(const float4*)(bpn + 4);
        float4 nB0 = *(const float4*)(bpn + 32);
        float4 nB1 = *(const float4*)(bpn + 36);

        #pragma unroll
        for (int s = 0; s < 2; ++s) {
            const int mloc = wv * 64 + s * 32 + kg * 8;
            float4 bv0 = s ? uB0 : uA0;
            float4 bv1 = s ? uB1 : uA1;
            float bbl[8] = {bv0.x * LOG2E, bv0.y * LOG2E, bv0.z * LOG2E, bv0.w * LOG2E,
                            bv1.x * LOG2E, bv1.y * LOG2E, bv1.z * LOG2E, bv1.w * LOG2E};
            #pragma unroll
            for (int h = 0; h < 8; ++h) {
                const float* f2p = f2L + h * 264 + mloc;
                float4 f2a = *(const float4*)f2p;
                float4 f2b = *(const float4*)(f2p + 4);
                float f2arr[8] = {f2a.x, f2a.y, f2a.z, f2a.w, f2b.x, f2b.y, f2b.z, f2b.w};
                f16x8 bf = *(const f16x8*)(ftsL + rowsel + h * hstep + mloc);
                union { f16x8 v; f16 e[8]; } af;
                #pragma unroll
                for (int j = 0; j < 8; ++j) {
                    float t1 = f2arr[j] + A1[h];
                    float t2 = fmaf(0.01f, f2arr[j], B1[h]);
                    af.e[j] = (f16)__builtin_amdgcn_exp2f(fmaxf(t1, t2) + bbl[j]);
                }
                acc[h] = __builtin_amdgcn_mfma_f32_16x16x32_f16(af.v, bf, acc[h], 0, 0, 0);
            }
        }
        __syncthreads();   // all waves done reading LDS for chunk ch
        if (ch < 15) {
            COMMIT();                      // write chunk ch+1 (regs ready)
            if (ch < 14) ISSUE(ch + 2);    // in flight during next compute
            __syncthreads();               // chunk ch+1 visible
        }
        uA0 = nA0; uA1 = nA1; uB0 = nB0; uB1 = nB1;
    }
#undef ISSUE
#undef COMMIT

    // epilogue: cross-wave reduction of D-frags (+denominator col 8) via LDS
    float* red = (float*)smem;  // [4][8][16][9]
    #pragma unroll
    for (int h = 0; h < 8; ++h) {
        if (c <= 8) {
            #pragma unroll
            for (int r = 0; r < 4; ++r)
                red[((wv * 8 + h) * 16 + kg * 4 + r) * 9 + c] = acc[h][r];
        }
    }
    __syncthreads();
    #pragma unroll
    for (int rep = 0; rep < 4; ++rep) {
        int idx = tid + rep * 256;
        int R = idx >> 6, hd = idx & 63;
        int h = hd >> 3, d = hd & 7;
        float v = 0.f, l = 0.f;
        #pragma unroll
        for (int w = 0; w < 4; ++w) {
            v += red[((w * 8 + h) * 16 + R) * 9 + d];
            l += red[((w * 8 + h) * 16 + R) * 9 + 8];
        }
        float o = v / l + h_bias[(p * 8 + h) * 8 + d];
        o = o > 0.f ? o : (__builtin_amdgcn_exp2f(o * LOG2E) - 1.0f);  // elu
        multi[((size_t)(n0 + R) * NP + p) * HD + hd] = o;
    }
}

// ---------------------------------------------------------------------------
// Kernel C: semantic attention + classifier. 16 nodes per block.
// ---------------------------------------------------------------------------
__global__ __launch_bounds__(256) void kC(const float* __restrict__ Ws,
                                          const float* __restrict__ bsv,
                                          const float* __restrict__ uv,
                                          const float* __restrict__ Wc,
                                          const float* __restrict__ bcv,
                                          char* __restrict__ ws,
                                          float* __restrict__ out) {
    __shared__ float WsL[64 * 128];
    __shared__ float mult[16 * 3 * 64];
    __shared__ float WcL[64 * 16];
    __shared__ float uL[128], bsL[128], bcL[16];
    __shared__ float vred[16 * 3 * 16];
    __shared__ float alphaL[16 * 3];
    __shared__ float fin[16 * 64];
    const int tid = threadIdx.x;
    const int n0 = blockIdx.x * 16;
    const float* multi = (const float*)(ws + OFF_MULTI);

    for (int i = tid; i < 64 * 128; i += 256) WsL[i] = Ws[i];
    for (int i = tid; i < 3072; i += 256) mult[i] = multi[(size_t)n0 * 192 + i];
    for (int i = tid; i < 1024; i += 256) WcL[i] = Wc[i];
    if (tid < 128) { uL[tid] = uv[tid]; bsL[tid] = bsv[tid]; }
    if (tid < 16) bcL[tid] = bcv[tid];
    __syncthreads();

    const int nl = tid >> 4, j = tid & 15;
    for (int p = 0; p < 3; ++p) {
        float va[8] = {};
        for (int e = 0; e < 64; ++e) {
            float me = mult[(nl * 3 + p) * 64 + e];
            #pragma unroll
            for (int i = 0; i < 8; ++i) va[i] += me * WsL[e * 128 + j + 16 * i];
        }
        float part = 0.f;
        #pragma unroll
        for (int i = 0; i < 8; ++i) part += tanhf(va[i] + bsL[j + 16 * i]) * uL[j + 16 * i];
        vred[(nl * 3 + p) * 16 + j] = part;
    }
    __syncthreads();
    if (tid < 16) {
        float sc[3];
        for (int p = 0; p < 3; ++p) {
            float s = 0.f;
            for (int jj = 0; jj < 16; ++jj) s += vred[(tid * 3 + p) * 16 + jj];
            sc[p] = s;
        }
        float mx = fmaxf(sc[0], fmaxf(sc[1], sc[2]));
        float e0 = __builtin_amdgcn_exp2f((sc[0] - mx) * LOG2E);
        float e1 = __builtin_amdgcn_exp2f((sc[1] - mx) * LOG2E);
        float e2 = __builtin_amdgcn_exp2f((sc[2] - mx) * LOG2E);
        float inv = 1.f / (e0 + e1 + e2);
        float a0 = e0 * inv, a1 = e1 * inv, a2 = e2 * inv;
        alphaL[tid * 3 + 0] = a0; alphaL[tid * 3 + 1] = a1; alphaL[tid * 3 + 2] = a2;
        out[OUT_ALPHA + (size_t)(n0 + tid) * 3 + 0] = a0;
        out[OUT_ALPHA + (size_t)(n0 + tid) * 3 + 1] = a1;
        out[OUT_ALPHA + (size_t)(n0 + tid) * 3 + 2] = a2;
    }
    __syncthreads();
    for (int idx = tid; idx < 1024; idx += 256) {
        int nn2 = idx >> 6, e = idx & 63;
        float f = 0.f;
        for (int p = 0; p < 3; ++p) f += mult[(nn2 * 3 + p) * 64 + e] * alphaL[nn2 * 3 + p];
        fin[nn2 * 64 + e] = f;
        out[OUT_FINAL + (size_t)(n0 + nn2) * 64 + e] = f;
    }
    __syncthreads();
    {
        int nn2 = tid >> 4, cc2 = tid & 15;
        float lg = bcL[cc2];
        for (int e = 0; e < 64; ++e) lg += fin[nn2 * 64 + e] * WcL[e * 16 + cc2];
        out[(size_t)(n0 + nn2) * 16 + cc2] = lg;
    }
}

extern "C" void kernel_launch(void* const* d_in, const int* in_sizes, int n_in,
                              void* d_out, int out_size, void* d_ws, size_t ws_size,
                              hipStream_t stream) {
    (void)in_sizes; (void)n_in; (void)out_size; (void)ws_size;
    const float* inp = (const float*)d_in[0];
    const float* bias = (const float*)d_in[1];
    const float* W = (const float*)d_in[2];
    const float* a1w = (const float*)d_in[3];
    const float* a1b = (const float*)d_in[4];
    const float* a2w = (const float*)d_in[5];
    const float* a2b = (const float*)d_in[6];
    const float* hb = (const float*)d_in[7];
    const float* Wsv = (const float*)d_in[8];
    const float* bsv = (const float*)d_in[9];
    const float* uv = (const float*)d_in[10];
    const float* Wcv = (const float*)d_in[11];
    const float* bcv = (const float*)d_in[12];
    char* ws = (char*)d_ws;
    float* out = (float*)d_out;

    hipLaunchKernelGGL(kA, dim3(128, 3), dim3(256), 0, stream, inp, W, a1w, a1b, a2w, a2b, ws);
    hipLaunchKernelGGL(kA2, dim3(24), dim3(64), 0, stream, ws);
    hipLaunchKernelGGL(kB, dim3(256, 3), dim3(256), 0, stream, bias, hb, ws);
    hipLaunchKernelGGL(kC, dim3(256), dim3(256), 0, stream, Wsv, bsv, uv, Wcv, bcv, ws, out);
}

// Round 6
// 413.744 us; speedup vs baseline: 1.2491x; 1.0291x over previous
//
#include <hip/hip_runtime.h>

#define LOG2E 1.44269504088896f

typedef _Float16 f16;
typedef _Float16 f16x8 __attribute__((ext_vector_type(8)));
typedef float f32x4 __attribute__((ext_vector_type(4)));

#define NP 3
#define NN 4096
#define FF 1024
#define HH 8
#define DD 8
#define HD 64

// workspace byte offsets
#define OFF_F1S   0            // f32 [3][8][4096]      (f1 * log2e)
#define OFF_F2S   393216       // f16 [3][8][4096]      (f2 * log2e)
#define OFF_F2MAX 589824       // f32 [24]              (max_m f2s)
#define OFF_FTST  590080       // f16 [3][64][4096]     (fts transposed: [p][hd][n])
#define OFF_MULTI 2162944      // f32 [4096][3][64]     (per-path embeddings)

// output float offsets
#define OUT_FINAL 65536        // 4096*16
#define OUT_ALPHA 327680       // 65536 + 4096*64

// ---------------------------------------------------------------------------
// Kernel A: fts[p][n][hd] = inputs[p] @ W[p] (fp32), then f1/f2 epilogue and
// transposed fp16 copy of fts. 32 rows per block (grid 384). T14 async-stage:
// next k-block's A (1 float4) and B (2 float4, thread->(k,h) contiguous W
// loads; W is L2-resident) are issued into NAMED registers before computing
// the current k-block and committed to LDS after the barrier -- removes the
// ~800cy HBM staging latency from the critical path (kA is grid-limited to
// 1.5 blocks/CU, so there is no TLP to hide it otherwise).
// ---------------------------------------------------------------------------
__global__ __launch_bounds__(256) void kA(const float* __restrict__ inp,
                                          const float* __restrict__ W,
                                          const float* __restrict__ a1w,
                                          const float* __restrict__ a1b,
                                          const float* __restrict__ a2w,
                                          const float* __restrict__ a2b,
                                          char* __restrict__ ws) {
    __shared__ float At[32 * 34];     // [k][row] transposed A tile (pad 34)
    __shared__ float Bt[32 * 64];     // [k][hd]
    __shared__ float ftile[32 * 68];  // [row][hd]
    const int tid = threadIdx.x;
    const int p = blockIdx.y;
    const int n0 = blockIdx.x * 32;

    const int tr = tid >> 4, tc = tid & 15;
    const int r0 = tr * 2, c0 = tc * 4;       // 2 rows x 4 cols per thread
    const int sr = tid >> 3, sak = (tid & 7) * 4;  // A staging: row, k-quad
    const int bk = tid >> 3, bh = tid & 7;    // B staging: k, head

    const float* aP = inp + ((size_t)p * NN + n0 + sr) * FF + sak;
    const float* bP = W + (((size_t)p * HH + bh) * FF + bk) * DD;
    float* bDst = &Bt[bk * 64 + bh * 8];

    // T14 staging state: named registers
    float4 pa, pb0, pb1;

#define KA_ISSUE(kb) do { \
        pa = *(const float4*)(aP + (kb) * 32); \
        const float* bp_ = bP + (size_t)(kb) * 32 * DD; \
        pb0 = *(const float4*)(bp_); \
        pb1 = *(const float4*)(bp_ + 4); \
    } while (0)

#define KA_COMMIT() do { \
        At[(sak + 0) * 34 + sr] = pa.x; \
        At[(sak + 1) * 34 + sr] = pa.y; \
        At[(sak + 2) * 34 + sr] = pa.z; \
        At[(sak + 3) * 34 + sr] = pa.w; \
        *(float4*)(bDst) = pb0; \
        *(float4*)(bDst + 4) = pb1; \
    } while (0)

    float acc[2][4] = {};

    KA_ISSUE(0);
    KA_COMMIT();
    KA_ISSUE(1);
    __syncthreads();

    #pragma unroll 1
    for (int kb = 0; kb < 32; ++kb) {
        #pragma unroll
        for (int k = 0; k < 32; ++k) {
            float2 a2 = *(const float2*)&At[k * 34 + r0];
            float4 bv = *(const float4*)&Bt[k * 64 + c0];
            float bb4[4] = {bv.x, bv.y, bv.z, bv.w};
            #pragma unroll
            for (int j = 0; j < 4; ++j) {
                acc[0][j] += a2.x * bb4[j];
                acc[1][j] += a2.y * bb4[j];
            }
        }
        __syncthreads();
        if (kb < 31) {
            KA_COMMIT();                     // write k-block kb+1 (regs ready)
            if (kb < 30) KA_ISSUE(kb + 2);   // in flight during next compute
            __syncthreads();
        }
    }
#undef KA_ISSUE
#undef KA_COMMIT

    // write fts tile to LDS
    #pragma unroll
    for (int i = 0; i < 2; ++i) {
        float4 o;
        o.x = acc[i][0]; o.y = acc[i][1]; o.z = acc[i][2]; o.w = acc[i][3];
        *(float4*)&ftile[(r0 + i) * 68 + c0] = o;
    }
    __syncthreads();

    float* f1s = (float*)(ws + OFF_F1S);
    f16* f2s = (f16*)(ws + OFF_F2S);
    // f1/f2 epilogue: exactly 256 tasks (32 rows x 8 heads)
    {
        int row = tid >> 3, h = tid & 7;
        const float* fb = &ftile[row * 68 + h * 8];
        float s1 = a1b[p * HH + h], s2 = a2b[p * HH + h];
        #pragma unroll
        for (int d = 0; d < 8; ++d) {
            float v = fb[d];
            s1 += v * a1w[((size_t)p * HH + h) * DD + d];
            s2 += v * a2w[((size_t)p * HH + h) * DD + d];
        }
        f1s[((size_t)p * HH + h) * NN + n0 + row] = s1 * LOG2E;
        f2s[((size_t)p * HH + h) * NN + n0 + row] = (f16)(s2 * LOG2E);
    }
    // transposed fp16 fts: ftsT[p][hd][n] (64 hd x 4 row-groups of 8)
    {
        f16* ftsT = (f16*)(ws + OFF_FTST);
        int cc2 = tid >> 2, rq = (tid & 3) * 8;
        union { f16 h[8]; uint4 u; } pk;
        #pragma unroll
        for (int i = 0; i < 8; ++i) pk.h[i] = (f16)ftile[(rq + i) * 68 + cc2];
        *(uint4*)(ftsT + ((size_t)p * HD + cc2) * NN + n0 + rq) = pk.u;
    }
}

// ---------------------------------------------------------------------------
// Kernel A2: f2smax[p][h] = max_m f2s[p][h][m]  (for the softmax upper bound)
// ---------------------------------------------------------------------------
__global__ __launch_bounds__(64) void kA2(char* __restrict__ ws) {
    const f16* f2s = (const f16*)(ws + OFF_F2S);
    float* fmax = (float*)(ws + OFF_F2MAX);
    int b = blockIdx.x;
    int lane = threadIdx.x;
    float v = -1e30f;
    for (int m = lane; m < NN; m += 64) v = fmaxf(v, (float)f2s[(size_t)b * NN + m]);
    #pragma unroll
    for (int off = 32; off >= 1; off >>= 1) v = fmaxf(v, __shfl_xor(v, off, 64));
    if (lane == 0) fmax[b] = v;
}

// ---------------------------------------------------------------------------
// Kernel B: fused attention, T14 async-STAGE split, spill-proofed (named
// uint4 registers; __launch_bounds__(256,3)). Validated r5: 125us, WRITE_SIZE
// 3072, VALUBusy 59%. Residual 4.3e6 bank conflicts are inherent b128 width
// (512B/wave > 128B/clk), not a layout bug. FROZEN this round (kA A/B).
// ---------------------------------------------------------------------------
__global__ __launch_bounds__(256, 3) void kB(const float* __restrict__ bias,
                                             const float* __restrict__ h_bias,
                                             char* __restrict__ ws) {
    __shared__ __align__(16) char smem[42768];
    f16* ftsL = (f16*)smem;               // [65][264] f16, row 64 = ones
    float* f2L = (float*)(smem + 34320);  // [8][264] f32

    const int tid = threadIdx.x;
    const int lane = tid & 63, wv = tid >> 6;
    const int c = lane & 15, kg = lane >> 4;
    const int p = blockIdx.y;
    const int n0 = blockIdx.x * 16;
    const int n = n0 + c;

    const float* f1s = (const float*)(ws + OFF_F1S);
    const f16* f2s = (const f16*)(ws + OFF_F2S);
    const float* fmax = (const float*)(ws + OFF_F2MAX);
    const f16* ftsG = (const f16*)(ws + OFF_FTST);
    float* multi = (float*)(ws + OFF_MULTI);

    // Per-head constants with -ub folded in:
    //   max(x,0.01x)-ub = max(x-ub, 0.01x-ub), x = f1+f2 (log2e-scaled)
    float A1[8], B1[8];
    #pragma unroll
    for (int h = 0; h < 8; ++h) {
        float f1v = f1s[((size_t)p * 8 + h) * NN + n];
        float fm = fmax[p * 8 + h];
        float x = f1v + fm;
        float lr = fmaxf(x, 0.01f * x);
        float ub = lr + 8.0f * LOG2E;  // bias < 8 assumed (N(0,1), max~5.95)
        A1[h] = f1v - ub;
        B1[h] = fmaf(0.01f, f1v, -ub);
    }

    // ones row for the denominator column
    for (int i = tid; i < 264; i += 256) ftsL[64 * 264 + i] = (f16)1.0f;

    // staging indices: 8-lane group sg covers a contiguous 128B row segment
    const int sg = tid >> 3, se = tid & 7;        // group, element-in-group
    const int srow = sg & 7, sq = sg >> 3;        // base row, column quarter
    const int f2r = tid >> 5, f2c = (tid & 31) * 8;  // f2 staging

    const f16* ftsP = ftsG + (size_t)p * HD * NN + sq * 64 + se * 8;
    const f16* f2P = f2s + (size_t)p * 8 * NN + (size_t)f2r * NN + f2c;
    f16* ldst = ftsL + srow * 264 + sq * 64 + se * 8;

    // per-h LDS row select for the MFMA B operand (row 64 = ones for c>=8)
    const int rowsel = (c < 8) ? c * 264 : 64 * 264;
    const int hstep = (c < 8) ? 8 * 264 : 0;

    const float* bb_base = bias + ((size_t)p * NN + n) * NN + wv * 64 + kg * 8;

    f32x4 acc[8] = {};

    // T14 staging state: NAMED registers (never an indexed array)
    uint4 r0, r1, r2, r3, r4, r5, r6, r7, rv;

#define ISSUE(ch) do { \
        const f16* gs_ = ftsP + (ch) * 256; \
        r0 = *(const uint4*)(gs_ + (size_t)(srow +  0) * NN); \
        r1 = *(const uint4*)(gs_ + (size_t)(srow +  8) * NN); \
        r2 = *(const uint4*)(gs_ + (size_t)(srow + 16) * NN); \
        r3 = *(const uint4*)(gs_ + (size_t)(srow + 24) * NN); \
        r4 = *(const uint4*)(gs_ + (size_t)(srow + 32) * NN); \
        r5 = *(const uint4*)(gs_ + (size_t)(srow + 40) * NN); \
        r6 = *(const uint4*)(gs_ + (size_t)(srow + 48) * NN); \
        r7 = *(const uint4*)(gs_ + (size_t)(srow + 56) * NN); \
        rv = *(const uint4*)(f2P + (ch) * 256); \
    } while (0)

#define COMMIT() do { \
        *(uint4*)(ldst + 0 * 8 * 264) = r0; \
        *(uint4*)(ldst + 1 * 8 * 264) = r1; \
        *(uint4*)(ldst + 2 * 8 * 264) = r2; \
        *(uint4*)(ldst + 3 * 8 * 264) = r3; \
        *(uint4*)(ldst + 4 * 8 * 264) = r4; \
        *(uint4*)(ldst + 5 * 8 * 264) = r5; \
        *(uint4*)(ldst + 6 * 8 * 264) = r6; \
        *(uint4*)(ldst + 7 * 8 * 264) = r7; \
        union { uint4 u; f16 h[8]; } t16_; \
        t16_.u = rv; \
        float4 lo_, hi_; \
        lo_.x = (float)t16_.h[0]; lo_.y = (float)t16_.h[1]; \
        lo_.z = (float)t16_.h[2]; lo_.w = (float)t16_.h[3]; \
        hi_.x = (float)t16_.h[4]; hi_.y = (float)t16_.h[5]; \
        hi_.z = (float)t16_.h[6]; hi_.w = (float)t16_.h[7]; \
        *(float4*)(f2L + f2r * 264 + f2c) = lo_; \
        *(float4*)(f2L + f2r * 264 + f2c + 4) = hi_; \
    } while (0)

    // prologue: stage chunk 0, issue chunk 1, load bias chunk 0
    ISSUE(0);
    COMMIT();
    ISSUE(1);
    float4 uA0 = *(const float4*)(bb_base);
    float4 uA1 = *(const float4*)(bb_base + 4);
    float4 uB0 = *(const float4*)(bb_base + 32);
    float4 uB1 = *(const float4*)(bb_base + 36);
    __syncthreads();

    #pragma unroll 1
    for (int ch = 0; ch < 16; ++ch) {
        // prefetch bias for next chunk (clamped; last iter re-reads, cached)
        const int chn = (ch + 1 < 16) ? ch + 1 : 15;
        const float* bpn = bb_base + chn * 256;
        float4 nA0 = *(const float4*)(bpn);
        float4 nA1 = *(const float4*)(bpn + 4);
        float4 nB0 = *(const float4*)(bpn + 32);
        float4 nB1 = *(const float4*)(bpn + 36);

        #pragma unroll
        for (int s = 0; s < 2; ++s) {
            const int mloc = wv * 64 + s * 32 + kg * 8;
            float4 bv0 = s ? uB0 : uA0;
            float4 bv1 = s ? uB1 : uA1;
            float bbl[8] = {bv0.x * LOG2E, bv0.y * LOG2E, bv0.z * LOG2E, bv0.w * LOG2E,
                            bv1.x * LOG2E, bv1.y * LOG2E, bv1.z * LOG2E, bv1.w * LOG2E};
            #pragma unroll
            for (int h = 0; h < 8; ++h) {
                const float* f2p = f2L + h * 264 + mloc;
                float4 f2a = *(const float4*)f2p;
                float4 f2b = *(const float4*)(f2p + 4);
                float f2arr[8] = {f2a.x, f2a.y, f2a.z, f2a.w, f2b.x, f2b.y, f2b.z, f2b.w};
                f16x8 bf = *(const f16x8*)(ftsL + rowsel + h * hstep + mloc);
                union { f16x8 v; f16 e[8]; } af;
                #pragma unroll
                for (int j = 0; j < 8; ++j) {
                    float t1 = f2arr[j] + A1[h];
                    float t2 = fmaf(0.01f, f2arr[j], B1[h]);
                    af.e[j] = (f16)__builtin_amdgcn_exp2f(fmaxf(t1, t2) + bbl[j]);
                }
                acc[h] = __builtin_amdgcn_mfma_f32_16x16x32_f16(af.v, bf, acc[h], 0, 0, 0);
            }
        }
        __syncthreads();   // all waves done reading LDS for chunk ch
        if (ch < 15) {
            COMMIT();                      // write chunk ch+1 (regs ready)
            if (ch < 14) ISSUE(ch + 2);    // in flight during next compute
            __syncthreads();               // chunk ch+1 visible
        }
        uA0 = nA0; uA1 = nA1; uB0 = nB0; uB1 = nB1;
    }
#undef ISSUE
#undef COMMIT

    // epilogue: cross-wave reduction of D-frags (+denominator col 8) via LDS
    float* red = (float*)smem;  // [4][8][16][9]
    #pragma unroll
    for (int h = 0; h < 8; ++h) {
        if (c <= 8) {
            #pragma unroll
            for (int r = 0; r < 4; ++r)
                red[((wv * 8 + h) * 16 + kg * 4 + r) * 9 + c] = acc[h][r];
        }
    }
    __syncthreads();
    #pragma unroll
    for (int rep = 0; rep < 4; ++rep) {
        int idx = tid + rep * 256;
        int R = idx >> 6, hd = idx & 63;
        int h = hd >> 3, d = hd & 7;
        float v = 0.f, l = 0.f;
        #pragma unroll
        for (int w = 0; w < 4; ++w) {
            v += red[((w * 8 + h) * 16 + R) * 9 + d];
            l += red[((w * 8 + h) * 16 + R) * 9 + 8];
        }
        float o = v / l + h_bias[(p * 8 + h) * 8 + d];
        o = o > 0.f ? o : (__builtin_amdgcn_exp2f(o * LOG2E) - 1.0f);  // elu
        multi[((size_t)(n0 + R) * NP + p) * HD + hd] = o;
    }
}

// ---------------------------------------------------------------------------
// Kernel C: semantic attention + classifier. 16 nodes per block.
// ---------------------------------------------------------------------------
__global__ __launch_bounds__(256) void kC(const float* __restrict__ Ws,
                                          const float* __restrict__ bsv,
                                          const float* __restrict__ uv,
                                          const float* __restrict__ Wc,
                                          const float* __restrict__ bcv,
                                          char* __restrict__ ws,
                                          float* __restrict__ out) {
    __shared__ float WsL[64 * 128];
    __shared__ float mult[16 * 3 * 64];
    __shared__ float WcL[64 * 16];
    __shared__ float uL[128], bsL[128], bcL[16];
    __shared__ float vred[16 * 3 * 16];
    __shared__ float alphaL[16 * 3];
    __shared__ float fin[16 * 64];
    const int tid = threadIdx.x;
    const int n0 = blockIdx.x * 16;
    const float* multi = (const float*)(ws + OFF_MULTI);

    for (int i = tid; i < 64 * 128; i += 256) WsL[i] = Ws[i];
    for (int i = tid; i < 3072; i += 256) mult[i] = multi[(size_t)n0 * 192 + i];
    for (int i = tid; i < 1024; i += 256) WcL[i] = Wc[i];
    if (tid < 128) { uL[tid] = uv[tid]; bsL[tid] = bsv[tid]; }
    if (tid < 16) bcL[tid] = bcv[tid];
    __syncthreads();

    const int nl = tid >> 4, j = tid & 15;
    for (int p = 0; p < 3; ++p) {
        float va[8] = {};
        for (int e = 0; e < 64; ++e) {
            float me = mult[(nl * 3 + p) * 64 + e];
            #pragma unroll
            for (int i = 0; i < 8; ++i) va[i] += me * WsL[e * 128 + j + 16 * i];
        }
        float part = 0.f;
        #pragma unroll
        for (int i = 0; i < 8; ++i) part += tanhf(va[i] + bsL[j + 16 * i]) * uL[j + 16 * i];
        vred[(nl * 3 + p) * 16 + j] = part;
    }
    __syncthreads();
    if (tid < 16) {
        float sc[3];
        for (int p = 0; p < 3; ++p) {
            float s = 0.f;
            for (int jj = 0; jj < 16; ++jj) s += vred[(tid * 3 + p) * 16 + jj];
            sc[p] = s;
        }
        float mx = fmaxf(sc[0], fmaxf(sc[1], sc[2]));
        float e0 = __builtin_amdgcn_exp2f((sc[0] - mx) * LOG2E);
        float e1 = __builtin_amdgcn_exp2f((sc[1] - mx) * LOG2E);
        float e2 = __builtin_amdgcn_exp2f((sc[2] - mx) * LOG2E);
        float inv = 1.f / (e0 + e1 + e2);
        float a0 = e0 * inv, a1 = e1 * inv, a2 = e2 * inv;
        alphaL[tid * 3 + 0] = a0; alphaL[tid * 3 + 1] = a1; alphaL[tid * 3 + 2] = a2;
        out[OUT_ALPHA + (size_t)(n0 + tid) * 3 + 0] = a0;
        out[OUT_ALPHA + (size_t)(n0 + tid) * 3 + 1] = a1;
        out[OUT_ALPHA + (size_t)(n0 + tid) * 3 + 2] = a2;
    }
    __syncthreads();
    for (int idx = tid; idx < 1024; idx += 256) {
        int nn2 = idx >> 6, e = idx & 63;
        float f = 0.f;
        for (int p = 0; p < 3; ++p) f += mult[(nn2 * 3 + p) * 64 + e] * alphaL[nn2 * 3 + p];
        fin[nn2 * 64 + e] = f;
        out[OUT_FINAL + (size_t)(n0 + nn2) * 64 + e] = f;
    }
    __syncthreads();
    {
        int nn2 = tid >> 4, cc2 = tid & 15;
        float lg = bcL[cc2];
        for (int e = 0; e < 64; ++e) lg += fin[nn2 * 64 + e] * WcL[e * 16 + cc2];
        out[(size_t)(n0 + nn2) * 16 + cc2] = lg;
    }
}

extern "C" void kernel_launch(void* const* d_in, const int* in_sizes, int n_in,
                              void* d_out, int out_size, void* d_ws, size_t ws_size,
                              hipStream_t stream) {
    (void)in_sizes; (void)n_in; (void)out_size; (void)ws_size;
    const float* inp = (const float*)d_in[0];
    const float* bias = (const float*)d_in[1];
    const float* W = (const float*)d_in[2];
    const float* a1w = (const float*)d_in[3];
    const float* a1b = (const float*)d_in[4];
    const float* a2w = (const float*)d_in[5];
    const float* a2b = (const float*)d_in[6];
    const float* hb = (const float*)d_in[7];
    const float* Wsv = (const float*)d_in[8];
    const float* bsv = (const float*)d_in[9];
    const float* uv = (const float*)d_in[10];
    const float* Wcv = (const float*)d_in[11];
    const float* bcv = (const float*)d_in[12];
    char* ws = (char*)d_ws;
    float* out = (float*)d_out;

    hipLaunchKernelGGL(kA, dim3(128, 3), dim3(256), 0, stream, inp, W, a1w, a1b, a2w, a2b, ws);
    hipLaunchKernelGGL(kA2, dim3(24), dim3(64), 0, stream, ws);
    hipLaunchKernelGGL(kB, dim3(256, 3), dim3(256), 0, stream, bias, hb, ws);
    hipLaunchKernelGGL(kC, dim3(256), dim3(256), 0, stream, Wsv, bsv, uv, Wcv, bcv, ws, out);
}

// Round 7
// 399.181 us; speedup vs baseline: 1.2947x; 1.0365x over previous
//
#include <hip/hip_runtime.h>

#define LOG2E 1.44269504088896f

typedef _Float16 f16;
typedef _Float16 f16x8 __attribute__((ext_vector_type(8)));
typedef float f32x4 __attribute__((ext_vector_type(4)));

#define NP 3
#define NN 4096
#define FF 1024
#define HH 8
#define DD 8
#define HD 64

// workspace byte offsets
#define OFF_F1S   0            // f32 [3][8][4096]      (f1 * log2e)
#define OFF_F2S   393216       // f16 [3][8][4096]      (f2 * log2e)
#define OFF_F2MAX 589824       // f32 [24]              (max_m f2s)
#define OFF_FTST  590080       // f16 [3][64][4096]     (fts transposed: [p][hd][n])
#define OFF_MULTI 2162944      // f32 [4096][3][64]     (per-path embeddings)
// k-split partial slabs (fp32 [3][4096][64] each). Slab0 aliases OFF_MULTI:
// multi is only written by kB, strictly after kAe has consumed the slabs.
#define OFF_FP0   2162944
#define OFF_FP1   5308672
#define SLAB_BYTES 3145728

// output float offsets
#define OUT_FINAL 65536        // 4096*16
#define OUT_ALPHA 327680       // 65536 + 4096*64

// ---------------------------------------------------------------------------
// Kernel A1: k-split partial GEMM. Grid (128, 3, 2): z = K-half. Each block
// computes a 32x64 partial over 512 K (16 kb-tiles) into slab[z]. 768 blocks
// = 3 blocks/CU = 12 waves/CU (the occupancy regime that made kB work);
// the old monolithic kA ran at 1.5 blocks/CU with every LDS/barrier stall
// exposed (~120us, hidden just under kB in top-5). T14 named-reg staging
// retained (proven at 3 blocks/CU in kB).
// ---------------------------------------------------------------------------
__global__ __launch_bounds__(256) void kA1(const float* __restrict__ inp,
                                           const float* __restrict__ W,
                                           char* __restrict__ ws) {
    __shared__ float At[32 * 34];     // [k][row] transposed A tile (pad 34)
    __shared__ float Bt[32 * 64];     // [k][hd]
    const int tid = threadIdx.x;
    const int p = blockIdx.y;
    const int n0 = blockIdx.x * 32;
    const int kb0 = blockIdx.z * 16;  // K-half: kb in [kb0, kb0+16)

    const int tr = tid >> 4, tc = tid & 15;
    const int r0 = tr * 2, c0 = tc * 4;       // 2 rows x 4 cols per thread
    const int sr = tid >> 3, sak = (tid & 7) * 4;  // A staging: row, k-quad
    const int bk = tid >> 3, bh = tid & 7;    // B staging: k, head

    const float* aP = inp + ((size_t)p * NN + n0 + sr) * FF + sak;
    const float* bP = W + (((size_t)p * HH + bh) * FF + bk) * DD;
    float* bDst = &Bt[bk * 64 + bh * 8];
    float* slab = (float*)(ws + OFF_FP0 + (size_t)blockIdx.z * SLAB_BYTES);

    // T14 staging state: named registers
    float4 pa, pb0, pb1;

#define KA_ISSUE(kb) do { \
        pa = *(const float4*)(aP + (kb) * 32); \
        const float* bp_ = bP + (size_t)(kb) * 32 * DD; \
        pb0 = *(const float4*)(bp_); \
        pb1 = *(const float4*)(bp_ + 4); \
    } while (0)

#define KA_COMMIT() do { \
        At[(sak + 0) * 34 + sr] = pa.x; \
        At[(sak + 1) * 34 + sr] = pa.y; \
        At[(sak + 2) * 34 + sr] = pa.z; \
        At[(sak + 3) * 34 + sr] = pa.w; \
        *(float4*)(bDst) = pb0; \
        *(float4*)(bDst + 4) = pb1; \
    } while (0)

    float acc[2][4] = {};

    KA_ISSUE(kb0);
    KA_COMMIT();
    KA_ISSUE(kb0 + 1);
    __syncthreads();

    #pragma unroll 1
    for (int kb = 0; kb < 16; ++kb) {
        #pragma unroll
        for (int k = 0; k < 32; ++k) {
            float2 a2 = *(const float2*)&At[k * 34 + r0];
            float4 bv = *(const float4*)&Bt[k * 64 + c0];
            float bb4[4] = {bv.x, bv.y, bv.z, bv.w};
            #pragma unroll
            for (int j = 0; j < 4; ++j) {
                acc[0][j] += a2.x * bb4[j];
                acc[1][j] += a2.y * bb4[j];
            }
        }
        __syncthreads();
        if (kb < 15) {
            KA_COMMIT();                           // write tile kb+1
            if (kb < 14) KA_ISSUE(kb0 + kb + 2);   // in flight during compute
            __syncthreads();
        }
    }
#undef KA_ISSUE
#undef KA_COMMIT

    // store partials directly (coalesced: 16 threads x float4 = 256B/row)
    #pragma unroll
    for (int i = 0; i < 2; ++i) {
        float4 o;
        o.x = acc[i][0]; o.y = acc[i][1]; o.z = acc[i][2]; o.w = acc[i][3];
        *(float4*)(slab + ((size_t)p * NN + n0 + r0 + i) * HD + c0) = o;
    }
}

// ---------------------------------------------------------------------------
// Kernel Ae: sum the two K-half slabs -> fts tile in LDS, then the f1/f2
// epilogue and transposed fp16 ftsT copy (same verified code as the original
// 64-row kA epilogue). Grid (64, 3), 256 threads, bulk-coalesced.
// ---------------------------------------------------------------------------
__global__ __launch_bounds__(256) void kAe(const float* __restrict__ a1w,
                                           const float* __restrict__ a1b,
                                           const float* __restrict__ a2w,
                                           const float* __restrict__ a2b,
                                           char* __restrict__ ws) {
    __shared__ float ftile[64 * 68];  // [row][hd]
    const int tid = threadIdx.x;
    const int p = blockIdx.y;
    const int n0 = blockIdx.x * 64;

    const float* s0 = (const float*)(ws + OFF_FP0) + ((size_t)p * NN + n0) * HD;
    const float* s1 = (const float*)(ws + OFF_FP1) + ((size_t)p * NN + n0) * HD;

    // each thread sums 16 contiguous floats (4 float4 per slab)
    {
        const int base = tid * 16;
        const int row = base >> 6, col = base & 63;
        #pragma unroll
        for (int q = 0; q < 4; ++q) {
            float4 u = *(const float4*)(s0 + base + q * 4);
            float4 v = *(const float4*)(s1 + base + q * 4);
            float4 o;
            o.x = u.x + v.x; o.y = u.y + v.y; o.z = u.z + v.z; o.w = u.w + v.w;
            *(float4*)&ftile[row * 68 + col + q * 4] = o;
        }
    }
    __syncthreads();

    float* f1s = (float*)(ws + OFF_F1S);
    f16* f2s = (f16*)(ws + OFF_F2S);
    // f1/f2 epilogue: 512 tasks (64 rows x 8 heads)
    #pragma unroll
    for (int rep = 0; rep < 2; ++rep) {
        int task = tid + rep * 256;
        int row = task >> 3, h = task & 7;
        const float* fb = &ftile[row * 68 + h * 8];
        float s1v = a1b[p * HH + h], s2v = a2b[p * HH + h];
        #pragma unroll
        for (int d = 0; d < 8; ++d) {
            float v = fb[d];
            s1v += v * a1w[((size_t)p * HH + h) * DD + d];
            s2v += v * a2w[((size_t)p * HH + h) * DD + d];
        }
        f1s[((size_t)p * HH + h) * NN + n0 + row] = s1v * LOG2E;
        f2s[((size_t)p * HH + h) * NN + n0 + row] = (f16)(s2v * LOG2E);
    }
    // transposed fp16 fts: ftsT[p][hd][n]
    {
        f16* ftsT = (f16*)(ws + OFF_FTST);
        int cc2 = tid >> 2, rq = (tid & 3) * 16;
        union { f16 h[16]; uint4 u[2]; } pk;
        #pragma unroll
        for (int i = 0; i < 16; ++i) pk.h[i] = (f16)ftile[(rq + i) * 68 + cc2];
        uint4* dst = (uint4*)(ftsT + ((size_t)p * HD + cc2) * NN + n0 + rq);
        dst[0] = pk.u[0];
        dst[1] = pk.u[1];
    }
}

// ---------------------------------------------------------------------------
// Kernel A2: f2smax[p][h] = max_m f2s[p][h][m]. Vectorized: 8 independent
// uint4 loads per lane (was 64 dependent scalar f16 loads, latency-bound at
// 24 waves on the whole GPU).
// ---------------------------------------------------------------------------
__global__ __launch_bounds__(64) void kA2(char* __restrict__ ws) {
    const f16* f2s = (const f16*)(ws + OFF_F2S);
    float* fmax = (float*)(ws + OFF_F2MAX);
    int b = blockIdx.x;
    int lane = threadIdx.x;
    float v = -1e30f;
    #pragma unroll
    for (int it = 0; it < 8; ++it) {
        union { uint4 u; f16 h[8]; } t;
        t.u = *(const uint4*)(f2s + (size_t)b * NN + ((size_t)it * 64 + lane) * 8);
        #pragma unroll
        for (int j = 0; j < 8; ++j) v = fmaxf(v, (float)t.h[j]);
    }
    #pragma unroll
    for (int off = 32; off >= 1; off >>= 1) v = fmaxf(v, __shfl_xor(v, off, 64));
    if (lane == 0) fmax[b] = v;
}

// ---------------------------------------------------------------------------
// Kernel B: fused attention, T14 async-STAGE split, spill-proofed (named
// uint4 registers; __launch_bounds__(256,3)). Validated r5/r6: 124us,
// WRITE_SIZE 3072, VALUBusy 59-60%. FROZEN (A/B control for the kA split).
// ---------------------------------------------------------------------------
__global__ __launch_bounds__(256, 3) void kB(const float* __restrict__ bias,
                                             const float* __restrict__ h_bias,
                                             char* __restrict__ ws) {
    __shared__ __align__(16) char smem[42768];
    f16* ftsL = (f16*)smem;               // [65][264] f16, row 64 = ones
    float* f2L = (float*)(smem + 34320);  // [8][264] f32

    const int tid = threadIdx.x;
    const int lane = tid & 63, wv = tid >> 6;
    const int c = lane & 15, kg = lane >> 4;
    const int p = blockIdx.y;
    const int n0 = blockIdx.x * 16;
    const int n = n0 + c;

    const float* f1s = (const float*)(ws + OFF_F1S);
    const f16* f2s = (const f16*)(ws + OFF_F2S);
    const float* fmax = (const float*)(ws + OFF_F2MAX);
    const f16* ftsG = (const f16*)(ws + OFF_FTST);
    float* multi = (float*)(ws + OFF_MULTI);

    // Per-head constants with -ub folded in:
    //   max(x,0.01x)-ub = max(x-ub, 0.01x-ub), x = f1+f2 (log2e-scaled)
    float A1[8], B1[8];
    #pragma unroll
    for (int h = 0; h < 8; ++h) {
        float f1v = f1s[((size_t)p * 8 + h) * NN + n];
        float fm = fmax[p * 8 + h];
        float x = f1v + fm;
        float lr = fmaxf(x, 0.01f * x);
        float ub = lr + 8.0f * LOG2E;  // bias < 8 assumed (N(0,1), max~5.95)
        A1[h] = f1v - ub;
        B1[h] = fmaf(0.01f, f1v, -ub);
    }

    // ones row for the denominator column
    for (int i = tid; i < 264; i += 256) ftsL[64 * 264 + i] = (f16)1.0f;

    // staging indices: 8-lane group sg covers a contiguous 128B row segment
    const int sg = tid >> 3, se = tid & 7;        // group, element-in-group
    const int srow = sg & 7, sq = sg >> 3;        // base row, column quarter
    const int f2r = tid >> 5, f2c = (tid & 31) * 8;  // f2 staging

    const f16* ftsP = ftsG + (size_t)p * HD * NN + sq * 64 + se * 8;
    const f16* f2P = f2s + (size_t)p * 8 * NN + (size_t)f2r * NN + f2c;
    f16* ldst = ftsL + srow * 264 + sq * 64 + se * 8;

    // per-h LDS row select for the MFMA B operand (row 64 = ones for c>=8)
    const int rowsel = (c < 8) ? c * 264 : 64 * 264;
    const int hstep = (c < 8) ? 8 * 264 : 0;

    const float* bb_base = bias + ((size_t)p * NN + n) * NN + wv * 64 + kg * 8;

    f32x4 acc[8] = {};

    // T14 staging state: NAMED registers (never an indexed array)
    uint4 r0, r1, r2, r3, r4, r5, r6, r7, rv;

#define ISSUE(ch) do { \
        const f16* gs_ = ftsP + (ch) * 256; \
        r0 = *(const uint4*)(gs_ + (size_t)(srow +  0) * NN); \
        r1 = *(const uint4*)(gs_ + (size_t)(srow +  8) * NN); \
        r2 = *(const uint4*)(gs_ + (size_t)(srow + 16) * NN); \
        r3 = *(const uint4*)(gs_ + (size_t)(srow + 24) * NN); \
        r4 = *(const uint4*)(gs_ + (size_t)(srow + 32) * NN); \
        r5 = *(const uint4*)(gs_ + (size_t)(srow + 40) * NN); \
        r6 = *(const uint4*)(gs_ + (size_t)(srow + 48) * NN); \
        r7 = *(const uint4*)(gs_ + (size_t)(srow + 56) * NN); \
        rv = *(const uint4*)(f2P + (ch) * 256); \
    } while (0)

#define COMMIT() do { \
        *(uint4*)(ldst + 0 * 8 * 264) = r0; \
        *(uint4*)(ldst + 1 * 8 * 264) = r1; \
        *(uint4*)(ldst + 2 * 8 * 264) = r2; \
        *(uint4*)(ldst + 3 * 8 * 264) = r3; \
        *(uint4*)(ldst + 4 * 8 * 264) = r4; \
        *(uint4*)(ldst + 5 * 8 * 264) = r5; \
        *(uint4*)(ldst + 6 * 8 * 264) = r6; \
        *(uint4*)(ldst + 7 * 8 * 264) = r7; \
        union { uint4 u; f16 h[8]; } t16_; \
        t16_.u = rv; \
        float4 lo_, hi_; \
        lo_.x = (float)t16_.h[0]; lo_.y = (float)t16_.h[1]; \
        lo_.z = (float)t16_.h[2]; lo_.w = (float)t16_.h[3]; \
        hi_.x = (float)t16_.h[4]; hi_.y = (float)t16_.h[5]; \
        hi_.z = (float)t16_.h[6]; hi_.w = (float)t16_.h[7]; \
        *(float4*)(f2L + f2r * 264 + f2c) = lo_; \
        *(float4*)(f2L + f2r * 264 + f2c + 4) = hi_; \
    } while (0)

    // prologue: stage chunk 0, issue chunk 1, load bias chunk 0
    ISSUE(0);
    COMMIT();
    ISSUE(1);
    float4 uA0 = *(const float4*)(bb_base);
    float4 uA1 = *(const float4*)(bb_base + 4);
    float4 uB0 = *(const float4*)(bb_base + 32);
    float4 uB1 = *(const float4*)(bb_base + 36);
    __syncthreads();

    #pragma unroll 1
    for (int ch = 0; ch < 16; ++ch) {
        // prefetch bias for next chunk (clamped; last iter re-reads, cached)
        const int chn = (ch + 1 < 16) ? ch + 1 : 15;
        const float* bpn = bb_base + chn * 256;
        float4 nA0 = *(const float4*)(bpn);
        float4 nA1 = *(const float4*)(bpn + 4);
        float4 nB0 = *(const float4*)(bpn + 32);
        float4 nB1 = *(const float4*)(bpn + 36);

        #pragma unroll
        for (int s = 0; s < 2; ++s) {
            const int mloc = wv * 64 + s * 32 + kg * 8;
            float4 bv0 = s ? uB0 : uA0;
            float4 bv1 = s ? uB1 : uA1;
            float bbl[8] = {bv0.x * LOG2E, bv0.y * LOG2E, bv0.z * LOG2E, bv0.w * LOG2E,
                            bv1.x * LOG2E, bv1.y * LOG2E, bv1.z * LOG2E, bv1.w * LOG2E};
            #pragma unroll
            for (int h = 0; h < 8; ++h) {
                const float* f2p = f2L + h * 264 + mloc;
                float4 f2a = *(const float4*)f2p;
                float4 f2b = *(const float4*)(f2p + 4);
                float f2arr[8] = {f2a.x, f2a.y, f2a.z, f2a.w, f2b.x, f2b.y, f2b.z, f2b.w};
                f16x8 bf = *(const f16x8*)(ftsL + rowsel + h * hstep + mloc);
                union { f16x8 v; f16 e[8]; } af;
                #pragma unroll
                for (int j = 0; j < 8; ++j) {
                    float t1 = f2arr[j] + A1[h];
                    float t2 = fmaf(0.01f, f2arr[j], B1[h]);
                    af.e[j] = (f16)__builtin_amdgcn_exp2f(fmaxf(t1, t2) + bbl[j]);
                }
                acc[h] = __builtin_amdgcn_mfma_f32_16x16x32_f16(af.v, bf, acc[h], 0, 0, 0);
            }
        }
        __syncthreads();   // all waves done reading LDS for chunk ch
        if (ch < 15) {
            COMMIT();                      // write chunk ch+1 (regs ready)
            if (ch < 14) ISSUE(ch + 2);    // in flight during next compute
            __syncthreads();               // chunk ch+1 visible
        }
        uA0 = nA0; uA1 = nA1; uB0 = nB0; uB1 = nB1;
    }
#undef ISSUE
#undef COMMIT

    // epilogue: cross-wave reduction of D-frags (+denominator col 8) via LDS
    float* red = (float*)smem;  // [4][8][16][9]
    #pragma unroll
    for (int h = 0; h < 8; ++h) {
        if (c <= 8) {
            #pragma unroll
            for (int r = 0; r < 4; ++r)
                red[((wv * 8 + h) * 16 + kg * 4 + r) * 9 + c] = acc[h][r];
        }
    }
    __syncthreads();
    #pragma unroll
    for (int rep = 0; rep < 4; ++rep) {
        int idx = tid + rep * 256;
        int R = idx >> 6, hd = idx & 63;
        int h = hd >> 3, d = hd & 7;
        float v = 0.f, l = 0.f;
        #pragma unroll
        for (int w = 0; w < 4; ++w) {
            v += red[((w * 8 + h) * 16 + R) * 9 + d];
            l += red[((w * 8 + h) * 16 + R) * 9 + 8];
        }
        float o = v / l + h_bias[(p * 8 + h) * 8 + d];
        o = o > 0.f ? o : (__builtin_amdgcn_exp2f(o * LOG2E) - 1.0f);  // elu
        multi[((size_t)(n0 + R) * NP + p) * HD + hd] = o;
    }
}

// ---------------------------------------------------------------------------
// Kernel C: semantic attention + classifier. 16 nodes per block. FROZEN.
// ---------------------------------------------------------------------------
__global__ __launch_bounds__(256) void kC(const float* __restrict__ Ws,
                                          const float* __restrict__ bsv,
                                          const float* __restrict__ uv,
                                          const float* __restrict__ Wc,
                                          const float* __restrict__ bcv,
                                          char* __restrict__ ws,
                                          float* __restrict__ out) {
    __shared__ float WsL[64 * 128];
    __shared__ float mult[16 * 3 * 64];
    __shared__ float WcL[64 * 16];
    __shared__ float uL[128], bsL[128], bcL[16];
    __shared__ float vred[16 * 3 * 16];
    __shared__ float alphaL[16 * 3];
    __shared__ float fin[16 * 64];
    const int tid = threadIdx.x;
    const int n0 = blockIdx.x * 16;
    const float* multi = (const float*)(ws + OFF_MULTI);

    for (int i = tid; i < 64 * 128; i += 256) WsL[i] = Ws[i];
    for (int i = tid; i < 3072; i += 256) mult[i] = multi[(size_t)n0 * 192 + i];
    for (int i = tid; i < 1024; i += 256) WcL[i] = Wc[i];
    if (tid < 128) { uL[tid] = uv[tid]; bsL[tid] = bsv[tid]; }
    if (tid < 16) bcL[tid] = bcv[tid];
    __syncthreads();

    const int nl = tid >> 4, j = tid & 15;
    for (int p = 0; p < 3; ++p) {
        float va[8] = {};
        for (int e = 0; e < 64; ++e) {
            float me = mult[(nl * 3 + p) * 64 + e];
            #pragma unroll
            for (int i = 0; i < 8; ++i) va[i] += me * WsL[e * 128 + j + 16 * i];
        }
        float part = 0.f;
        #pragma unroll
        for (int i = 0; i < 8; ++i) part += tanhf(va[i] + bsL[j + 16 * i]) * uL[j + 16 * i];
        vred[(nl * 3 + p) * 16 + j] = part;
    }
    __syncthreads();
    if (tid < 16) {
        float sc[3];
        for (int p = 0; p < 3; ++p) {
            float s = 0.f;
            for (int jj = 0; jj < 16; ++jj) s += vred[(tid * 3 + p) * 16 + jj];
            sc[p] = s;
        }
        float mx = fmaxf(sc[0], fmaxf(sc[1], sc[2]));
        float e0 = __builtin_amdgcn_exp2f((sc[0] - mx) * LOG2E);
        float e1 = __builtin_amdgcn_exp2f((sc[1] - mx) * LOG2E);
        float e2 = __builtin_amdgcn_exp2f((sc[2] - mx) * LOG2E);
        float inv = 1.f / (e0 + e1 + e2);
        float a0 = e0 * inv, a1 = e1 * inv, a2 = e2 * inv;
        alphaL[tid * 3 + 0] = a0; alphaL[tid * 3 + 1] = a1; alphaL[tid * 3 + 2] = a2;
        out[OUT_ALPHA + (size_t)(n0 + tid) * 3 + 0] = a0;
        out[OUT_ALPHA + (size_t)(n0 + tid) * 3 + 1] = a1;
        out[OUT_ALPHA + (size_t)(n0 + tid) * 3 + 2] = a2;
    }
    __syncthreads();
    for (int idx = tid; idx < 1024; idx += 256) {
        int nn2 = idx >> 6, e = idx & 63;
        float f = 0.f;
        for (int p = 0; p < 3; ++p) f += mult[(nn2 * 3 + p) * 64 + e] * alphaL[nn2 * 3 + p];
        fin[nn2 * 64 + e] = f;
        out[OUT_FINAL + (size_t)(n0 + nn2) * 64 + e] = f;
    }
    __syncthreads();
    {
        int nn2 = tid >> 4, cc2 = tid & 15;
        float lg = bcL[cc2];
        for (int e = 0; e < 64; ++e) lg += fin[nn2 * 64 + e] * WcL[e * 16 + cc2];
        out[(size_t)(n0 + nn2) * 16 + cc2] = lg;
    }
}

extern "C" void kernel_launch(void* const* d_in, const int* in_sizes, int n_in,
                              void* d_out, int out_size, void* d_ws, size_t ws_size,
                              hipStream_t stream) {
    (void)in_sizes; (void)n_in; (void)out_size; (void)ws_size;
    const float* inp = (const float*)d_in[0];
    const float* bias = (const float*)d_in[1];
    const float* W = (const float*)d_in[2];
    const float* a1w = (const float*)d_in[3];
    const float* a1b = (const float*)d_in[4];
    const float* a2w = (const float*)d_in[5];
    const float* a2b = (const float*)d_in[6];
    const float* hb = (const float*)d_in[7];
    const float* Wsv = (const float*)d_in[8];
    const float* bsv = (const float*)d_in[9];
    const float* uv = (const float*)d_in[10];
    const float* Wcv = (const float*)d_in[11];
    const float* bcv = (const float*)d_in[12];
    char* ws = (char*)d_ws;
    float* out = (float*)d_out;

    hipLaunchKernelGGL(kA1, dim3(128, 3, 2), dim3(256), 0, stream, inp, W, ws);
    hipLaunchKernelGGL(kAe, dim3(64, 3), dim3(256), 0, stream, a1w, a1b, a2w, a2b, ws);
    hipLaunchKernelGGL(kA2, dim3(24), dim3(64), 0, stream, ws);
    hipLaunchKernelGGL(kB, dim3(256, 3), dim3(256), 0, stream, bias, hb, ws);
    hipLaunchKernelGGL(kC, dim3(256), dim3(256), 0, stream, Wsv, bsv, uv, Wcv, bcv, ws, out);
}